// Round 6
// baseline (955.886 us; speedup 1.0000x reference)
//
#include <hip/hip_runtime.h>
#include <math.h>

typedef _Float16 h16;
typedef _Float16 v2h __attribute__((ext_vector_type(2)));

#define ALPHA 0.2f
#define MASKV -9000000000000000.0f

constexpr int GSCR = 268;   // floats per group scratch slot (268 mod 32 = 12 -> b128 reads of the 8 groups tile all 32 banks)
constexpr int O_S  = 0;     // s[27] f32
constexpr int O_F1 = 28;    // f1[27] f32  (also holds obs[9] during phase B; obs dead before f1 written)
constexpr int O_F2 = 56;    // f2[3][10] f32
constexpr int O_U  = 92;    // byte 368 (16B aligned): h1 tile [9][32] f16 (576B) / att [27][12] f16 (648B)
// h2 overlay lives at group base (floats 0..215): used only after s/f1/f2/att are dead.

#if defined(__has_builtin)
#  if __has_builtin(__builtin_amdgcn_fdot2)
#    define FDOT2(a,b,c) __builtin_amdgcn_fdot2((a),(b),(c),false)
#  endif
#endif
#ifndef FDOT2
__device__ __forceinline__ float fdot2_sw(v2h a, v2h b, float c) {
    return c + (float)a.x*(float)b.x + (float)a.y*(float)b.y;
}
#  define FDOT2(a,b,c) fdot2_sw((a),(b),(c))
#endif

union U4 { float4 f; v2h h[4]; };
union U2 { float2 f; v2h h[2]; };
union U1 { float  f; v2h h;    };

#define WAVE_SYNC() asm volatile("s_waitcnt lgkmcnt(0)" ::: "memory")

__device__ __forceinline__ float fast_rcp(float x) { return __builtin_amdgcn_rcpf(x); }
__device__ __forceinline__ float tanh_fast(float x) {
    float e = __expf(x + x);
    return 1.f - 2.f * fast_rcp(e + 1.f);
}

// ws layout (halves): [0,4608): w2H[c][i] (48x96)  [4608,5760): wp1P pair-slots:
//   wp1P[k][s] = { Wp1[c_lo][k], Wp1[c_hi][k] },  s=3*l8+kp, c_lo=l8+16*kp, c_hi=c_lo+8
__global__ void prep_kernel(const float* __restrict__ W2, const float* __restrict__ Wp1,
                            h16* __restrict__ ws) {
    int t = blockIdx.x * 256 + threadIdx.x;
    if (t < 48 * 96) {
        int c = t / 96, i = t - c * 96;
        int h = c >> 4, d = c & 15;
        ws[t] = (h16)W2[(h * 96 + i) * 16 + d];
    } else if (t < 48 * 96 + 576) {
        int t2 = t - 48 * 96;
        int k = t2 / 24, s = t2 - k * 24;
        int l = s / 3, kp = s - 3 * l;
        int clo = l + 16 * kp, chi = clo + 8;
        ws[4608 + 2 * t2]     = (h16)Wp1[clo * 24 + k];
        ws[4608 + 2 * t2 + 1] = (h16)Wp1[chi * 24 + k];
    }
}

// v6 = v4 + `#pragma unroll 1` on the three hoist-prone loops (C's it, D's ib,
// F+G's kk). With those loops fully unrolled, the scheduler hoists 18-24
// float4 loads (72-96 VGPRs of transients) while acc[9][6]=54 is live ->
// demand ~140-155 > the 128-reg budget -> ~40 dwords/iter of scratch spill
// = the persistent ~150 MB/way HBM traffic. Capping the hoist window to one
// iteration keeps peak demand < 110 with zero algorithmic change; ILP inside
// one ib (54 independent dot2 chains) still covers the 6 L1 + 9 LDS loads.
__global__ __launch_bounds__(128, 4) void gnn_gat_kernel(
    const float* __restrict__ obs, const float* __restrict__ adj,
    const float* __restrict__ W1,  const float* __restrict__ a1,
    const float* __restrict__ a2,  const float* __restrict__ bp1,
    const float* __restrict__ Wp2, const h16* __restrict__ ws,
    float* __restrict__ out, int B)
{
    __shared__ float sW1[96];
    __shared__ float sC12[6];
    __shared__ unsigned sRb[9];     // per-row 9-bit adjacency masks
    __shared__ __align__(16) float smem[16 * GSCR];

    const int tid = threadIdx.x;
    if (tid < 96) sW1[tid] = W1[tid];
    if (tid < 9) {
        unsigned u = 0;
        for (int j = 0; j < 9; ++j)
            u |= (adj[tid * 9 + j] > 0.f ? 1u : 0u) << j;
        sRb[tid] = u;
    }
    if (tid < 6) {
        int gg = tid >> 1, w = tid & 1;
        float s = 0.f;
        for (int d = 0; d < 32; ++d)
            s += W1[gg * 32 + d] * a1[gg * 64 + w * 32 + d];
        sC12[tid] = s;
    }
    __syncthreads();

    const int wv = tid >> 6, lane = tid & 63;
    const int q = lane >> 3, l8 = lane & 7;
    float* g = smem + (wv * 8 + q) * GSCR;
    float4* hUf4 = (float4*)(g + O_U);            // h1 tile rows: 4 float4 each
    float4* h2f4 = (float4*)g;                    // h2 rows: 6 float4 each
    const float4* wsf4 = (const float4*)ws;

    const int slots = gridDim.x * 16;
    for (int b = (blockIdx.x * 2 + wv) * 8 + q; b < B; b += slots) {
        // ---- A: obs into registers (static use only) + LDS copy (runtime use) ----
        float o_r[9];
        #pragma unroll
        for (int j = 0; j < 9; ++j) o_r[j] = obs[(size_t)b * 9 + j];
        g[O_F1 + l8] = obs[(size_t)b * 9 + l8];
        if (l8 == 0) g[O_F1 + 8] = obs[(size_t)b * 9 + 8];
        WAVE_SYNC();

        // ---- B: layer-1 collapsed attention -> s[g][n] in LDS ----
        #pragma unroll
        for (int it = 0; it < 4; ++it) {
            int t = l8 + 8 * it;
            if (t < 27) {
                int gg = (t >= 18) ? 2 : (t >= 9 ? 1 : 0);
                int n = t - 9 * gg;
                float f1 = sC12[2 * gg] * g[O_F1 + n];   // LDS lookups (runtime n, gg)
                float c2 = sC12[2 * gg + 1];
                unsigned rbits = sRb[n];
                float e[9], m = -3.0e38f;
                #pragma unroll
                for (int j = 0; j < 9; ++j) {
                    float x = f1 + c2 * o_r[j];
                    x = x > 0.f ? x : ALPHA * x;
                    x = ((rbits >> j) & 1) ? x : MASKV;
                    e[j] = x; m = fmaxf(m, x);
                }
                float sum = 0.f, sw = 0.f;
                #pragma unroll
                for (int j = 0; j < 9; ++j) {
                    float p = __expf(e[j] - m);
                    sum += p; sw += p * o_r[j];
                }
                g[O_S + t] = sw * fast_rcp(sum);
            }
        }
        WAVE_SYNC();

        // ---- C/D: 3 K-tiles of 32; h1 f16 in LDS, GEMM via v_dot2 ----
        float acc[9][6];
        #pragma unroll
        for (int n = 0; n < 9; ++n)
            #pragma unroll
            for (int k = 0; k < 6; ++k) acc[n][k] = 0.f;

        for (int p = 0; p < 3; ++p) {
            // C: h1[n][0..31] = elu(s[p][n] * W1[32p..32p+31]) as f16
            #pragma unroll 1
            for (int it = 0; it < 5; ++it) {
                int t = l8 + 8 * it;
                if (t < 36) {
                    int n = t >> 2, ib = t & 3;
                    int i0 = 32 * p + 8 * ib;
                    float sv = g[O_S + p * 9 + n];
                    float4 wa = *(const float4*)&sW1[i0];
                    float4 wb = *(const float4*)&sW1[i0 + 4];
                    float v0 = sv * wa.x, v1 = sv * wa.y, v2 = sv * wa.z, v3 = sv * wa.w;
                    float v4 = sv * wb.x, v5 = sv * wb.y, v6 = sv * wb.z, v7 = sv * wb.w;
                    v0 = v0 > 0.f ? v0 : __expf(v0) - 1.f;
                    v1 = v1 > 0.f ? v1 : __expf(v1) - 1.f;
                    v2 = v2 > 0.f ? v2 : __expf(v2) - 1.f;
                    v3 = v3 > 0.f ? v3 : __expf(v3) - 1.f;
                    v4 = v4 > 0.f ? v4 : __expf(v4) - 1.f;
                    v5 = v5 > 0.f ? v5 : __expf(v5) - 1.f;
                    v6 = v6 > 0.f ? v6 : __expf(v6) - 1.f;
                    v7 = v7 > 0.f ? v7 : __expf(v7) - 1.f;
                    U4 u;
                    u.h[0] = (v2h){(h16)v0, (h16)v1};
                    u.h[1] = (v2h){(h16)v2, (h16)v3};
                    u.h[2] = (v2h){(h16)v4, (h16)v5};
                    u.h[3] = (v2h){(h16)v6, (h16)v7};
                    hUf4[n * 4 + ib] = u.f;
                }
            }
            WAVE_SYNC();

            // D: acc[n][k] += h1[n][i:i+8] . w2[c][i:i+8]
            #pragma unroll 1
            for (int ib = 0; ib < 4; ++ib) {
                U4 w[6];
                #pragma unroll
                for (int k = 0; k < 6; ++k)
                    w[k].f = wsf4[(l8 + 8 * k) * 12 + p * 4 + ib];
                #pragma unroll
                for (int n = 0; n < 9; ++n) {
                    U4 hh; hh.f = hUf4[n * 4 + ib];
                    #pragma unroll
                    for (int k = 0; k < 6; ++k) {
                        float a = acc[n][k];
                        a = FDOT2(hh.h[0], w[k].h[0], a);
                        a = FDOT2(hh.h[1], w[k].h[1], a);
                        a = FDOT2(hh.h[2], w[k].h[2], a);
                        a = FDOT2(hh.h[3], w[k].h[3], a);
                        acc[n][k] = a;
                    }
                }
            }
            WAVE_SYNC();
        }

        // ---- f1/f2 for layer-2 attention (butterfly over 8 d-lanes) ----
        // a2 coefficients loaded at use (L1-hot, 384 B) instead of 12 regs.
        #pragma unroll
        for (int h = 0; h < 3; ++h) {
            float aa0 = a2[h * 32 + l8];
            float aa1 = a2[h * 32 + 8 + l8];
            float ab0 = a2[h * 32 + 16 + l8];
            float ab1 = a2[h * 32 + 24 + l8];
            #pragma unroll
            for (int n = 0; n < 9; ++n) {
                float v1 = acc[n][2 * h] * aa0 + acc[n][2 * h + 1] * aa1;
                float v2 = acc[n][2 * h] * ab0 + acc[n][2 * h + 1] * ab1;
                v1 += __shfl_xor(v1, 1, 8); v1 += __shfl_xor(v1, 2, 8); v1 += __shfl_xor(v1, 4, 8);
                v2 += __shfl_xor(v2, 1, 8); v2 += __shfl_xor(v2, 2, 8); v2 += __shfl_xor(v2, 4, 8);
                if (((h * 9 + n) & 7) == l8) {
                    g[O_F1 + h * 9 + n]  = v1;
                    g[O_F2 + h * 10 + n] = v2;
                }
            }
        }
        WAVE_SYNC();

        // ---- E1: att rows -> f16 LDS [27][12] ----
        #pragma unroll
        for (int it = 0; it < 4; ++it) {
            int t = l8 + 8 * it;
            if (t < 27) {
                int h = (t >= 18) ? 2 : (t >= 9 ? 1 : 0);
                int i = t - 9 * h;
                float f1i = g[O_F1 + t];
                unsigned rbits = sRb[i];
                float e[9], m = -3.0e38f;
                #pragma unroll
                for (int j = 0; j < 9; ++j) {
                    float x = f1i + g[O_F2 + h * 10 + j];   // direct LDS read
                    x = x > 0.f ? x : ALPHA * x;
                    x = ((rbits >> j) & 1) ? x : MASKV;
                    e[j] = x; m = fmaxf(m, x);
                }
                float p[9], sum = 0.f;
                #pragma unroll
                for (int j = 0; j < 9; ++j) { p[j] = __expf(e[j] - m); sum += p[j]; }
                float r = fast_rcp(sum);
                char* row = (char*)(g + O_U) + t * 24;
                U2 u01, u23; U1 u4;
                u01.h[0] = (v2h){(h16)(p[0] * r), (h16)(p[1] * r)};
                u01.h[1] = (v2h){(h16)(p[2] * r), (h16)(p[3] * r)};
                u23.h[0] = (v2h){(h16)(p[4] * r), (h16)(p[5] * r)};
                u23.h[1] = (v2h){(h16)(p[6] * r), (h16)(p[7] * r)};
                u4.h     = (v2h){(h16)(p[8] * r), (h16)0.f};
                *(float2*)(row)      = u01.f;
                *(float2*)(row + 8)  = u23.f;
                *(float*)(row + 16)  = u4.f;
            }
        }
        WAVE_SYNC();

        // ---- E2: h2 = att @ Wh2, in place into acc ----
        #pragma unroll
        for (int h = 0; h < 3; ++h) {
            float t0[9], t1[9];
            #pragma unroll
            for (int i = 0; i < 9; ++i) {
                const char* row = (const char*)(g + O_U) + (h * 9 + i) * 24;
                U2 a01, a23; U1 a4;
                a01.f = *(const float2*)row;
                a23.f = *(const float2*)(row + 8);
                a4.f  = *(const float*)(row + 16);
                float pj[9];
                pj[0] = (float)a01.h[0].x; pj[1] = (float)a01.h[0].y;
                pj[2] = (float)a01.h[1].x; pj[3] = (float)a01.h[1].y;
                pj[4] = (float)a23.h[0].x; pj[5] = (float)a23.h[0].y;
                pj[6] = (float)a23.h[1].x; pj[7] = (float)a23.h[1].y;
                pj[8] = (float)a4.h.x;
                float s0 = 0.f, s1 = 0.f;
                #pragma unroll
                for (int j = 0; j < 9; ++j) {
                    s0 += pj[j] * acc[j][2 * h];
                    s1 += pj[j] * acc[j][2 * h + 1];
                }
                t0[i] = s0; t1[i] = s1;
            }
            #pragma unroll
            for (int i = 0; i < 9; ++i) { acc[i][2 * h] = t0[i]; acc[i][2 * h + 1] = t1[i]; }
        }

        // ---- F0: pack h2 to f16 pair-slots in LDS (overlay at group base) ----
        #pragma unroll
        for (int n = 0; n < 9; ++n) {
            #pragma unroll
            for (int kp = 0; kp < 3; ++kp) {
                U1 u; u.h = (v2h){(h16)acc[n][2 * kp], (h16)acc[n][2 * kp + 1]};
                ((float*)g)[n * 24 + 3 * l8 + kp] = u.f;
            }
        }
        WAVE_SYNC();

        // ---- F+G: scores via dot2 against pre-packed Wp1; butterfly once per n ----
        // Wp2/bp1 scalars loaded at use (L1-hot) instead of 6 persistent regs.
        float sp[9];
        #pragma unroll
        for (int n = 0; n < 9; ++n) sp[n] = 0.f;
        #pragma unroll 1
        for (int kk = 0; kk < 3; ++kk) {
            int k = l8 + 8 * kk;
            float wqv = Wp2[k];
            float bqv = bp1[k];
            U4 w0, w1, w2u, w3, w4, w5;
            w0.f = wsf4[576 + k * 6 + 0];
            w1.f = wsf4[576 + k * 6 + 1];
            w2u.f = wsf4[576 + k * 6 + 2];
            w3.f = wsf4[576 + k * 6 + 3];
            w4.f = wsf4[576 + k * 6 + 4];
            w5.f = wsf4[576 + k * 6 + 5];
            #pragma unroll
            for (int n = 0; n < 9; ++n) {
                float a = 0.f;
                U4 x;
                x.f = h2f4[n * 6 + 0];
                a = FDOT2(x.h[0], w0.h[0], a); a = FDOT2(x.h[1], w0.h[1], a);
                a = FDOT2(x.h[2], w0.h[2], a); a = FDOT2(x.h[3], w0.h[3], a);
                x.f = h2f4[n * 6 + 1];
                a = FDOT2(x.h[0], w1.h[0], a); a = FDOT2(x.h[1], w1.h[1], a);
                a = FDOT2(x.h[2], w1.h[2], a); a = FDOT2(x.h[3], w1.h[3], a);
                x.f = h2f4[n * 6 + 2];
                a = FDOT2(x.h[0], w2u.h[0], a); a = FDOT2(x.h[1], w2u.h[1], a);
                a = FDOT2(x.h[2], w2u.h[2], a); a = FDOT2(x.h[3], w2u.h[3], a);
                x.f = h2f4[n * 6 + 3];
                a = FDOT2(x.h[0], w3.h[0], a); a = FDOT2(x.h[1], w3.h[1], a);
                a = FDOT2(x.h[2], w3.h[2], a); a = FDOT2(x.h[3], w3.h[3], a);
                x.f = h2f4[n * 6 + 4];
                a = FDOT2(x.h[0], w4.h[0], a); a = FDOT2(x.h[1], w4.h[1], a);
                a = FDOT2(x.h[2], w4.h[2], a); a = FDOT2(x.h[3], w4.h[3], a);
                x.f = h2f4[n * 6 + 5];
                a = FDOT2(x.h[0], w5.h[0], a); a = FDOT2(x.h[1], w5.h[1], a);
                a = FDOT2(x.h[2], w5.h[2], a); a = FDOT2(x.h[3], w5.h[3], a);
                float tv = tanh_fast(a + bqv);
                sp[n] += tv * wqv;
            }
        }
        #pragma unroll
        for (int n = 0; n < 9; ++n) {
            sp[n] += __shfl_xor(sp[n], 1, 8);
            sp[n] += __shfl_xor(sp[n], 2, 8);
            sp[n] += __shfl_xor(sp[n], 4, 8);
        }

        // ---- H: node softmax (bp2 cancels) + weighted sum -> out ----
        float mx = sp[0];
        #pragma unroll
        for (int n = 1; n < 9; ++n) mx = fmaxf(mx, sp[n]);
        float wn9[9], sum = 0.f;
        #pragma unroll
        for (int n = 0; n < 9; ++n) { wn9[n] = __expf(sp[n] - mx); sum += wn9[n]; }
        float r = fast_rcp(sum);
        #pragma unroll
        for (int k = 0; k < 6; ++k) {
            float ov = 0.f;
            #pragma unroll
            for (int n = 0; n < 9; ++n) ov += wn9[n] * acc[n][k];
            out[(size_t)b * 48 + l8 + 8 * k] = ov * r;
        }
        WAVE_SYNC();
    }
}

extern "C" void kernel_launch(void* const* d_in, const int* in_sizes, int n_in,
                              void* d_out, int out_size, void* d_ws, size_t ws_size,
                              hipStream_t stream) {
    const float* obs = (const float*)d_in[0];
    const float* adj = (const float*)d_in[1];
    const float* W1  = (const float*)d_in[2];
    const float* a1  = (const float*)d_in[3];
    const float* W2  = (const float*)d_in[4];
    const float* a2  = (const float*)d_in[5];
    const float* Wp1 = (const float*)d_in[6];
    const float* bp1 = (const float*)d_in[7];
    const float* Wp2 = (const float*)d_in[8];
    float* out = (float*)d_out;
    h16* ws = (h16*)d_ws;

    const int B = in_sizes[0] / 9;

    prep_kernel<<<(48 * 96 + 576 + 255) / 256, 256, 0, stream>>>(W2, Wp1, ws);

    gnn_gat_kernel<<<4096, 128, 0, stream>>>(
        obs, adj, W1, a1, a2, bp1, Wp2, ws, out, B);
}

// Round 7
// 313.342 us; speedup vs baseline: 3.0506x; 3.0506x over previous
//
#include <hip/hip_runtime.h>
#include <math.h>

typedef _Float16 h16;
typedef _Float16 v2h  __attribute__((ext_vector_type(2)));
typedef _Float16 f16x8 __attribute__((ext_vector_type(8)));
typedef float    f32x4 __attribute__((ext_vector_type(4)));

#define ALPHA 0.2f
#define MASKV -9000000000000000.0f

constexpr int GSCR = 268;   // floats per group scratch slot (268 mod 32 = 12)
constexpr int O_S  = 0;     // s[27] f32
constexpr int O_F1 = 28;    // f1[27] f32  (also holds obs[9] during phase B)
constexpr int O_F2 = 56;    // f2[3][10] f32
constexpr int O_U  = 92;    // byte 368 (16B aligned): h1 tile [9][32] f16 (576B) / att [27][12] f16 (648B)
constexpr int CBS  = 19;    // C-extract row stride (dwords); 72*19+15 < 8*GSCR
// h2 overlay lives at group base (floats 0..215): used only after s/f1/f2/att are dead.

#if defined(__has_builtin)
#  if __has_builtin(__builtin_amdgcn_fdot2)
#    define FDOT2(a,b,c) __builtin_amdgcn_fdot2((a),(b),(c),false)
#  endif
#endif
#ifndef FDOT2
__device__ __forceinline__ float fdot2_sw(v2h a, v2h b, float c) {
    return c + (float)a.x*(float)b.x + (float)a.y*(float)b.y;
}
#  define FDOT2(a,b,c) fdot2_sw((a),(b),(c))
#endif

union U4 { float4 f; v2h h[4]; };
union U2 { float2 f; v2h h[2]; };
union U1 { float  f; v2h h;    };

#define WAVE_SYNC() asm volatile("s_waitcnt lgkmcnt(0)" ::: "memory")

__device__ __forceinline__ float fast_rcp(float x) { return __builtin_amdgcn_rcpf(x); }
__device__ __forceinline__ float tanh_fast(float x) {
    float e = __expf(x + x);
    return 1.f - 2.f * fast_rcp(e + 1.f);
}

// ws layout (halves): [0,4608): w2H[c][i] (48x96)  [4608,5760): wp1P pair-slots:
//   wp1P[k][s] = { Wp1[c_lo][k], Wp1[c_hi][k] },  s=3*l8+kp, c_lo=l8+16*kp, c_hi=c_lo+8
__global__ void prep_kernel(const float* __restrict__ W2, const float* __restrict__ Wp1,
                            h16* __restrict__ ws) {
    int t = blockIdx.x * 256 + threadIdx.x;
    if (t < 48 * 96) {
        int c = t / 96, i = t - c * 96;
        int h = c >> 4, d = c & 15;
        ws[t] = (h16)W2[(h * 96 + i) * 16 + d];
    } else if (t < 48 * 96 + 576) {
        int t2 = t - 48 * 96;
        int k = t2 / 24, s = t2 - k * 24;
        int l = s / 3, kp = s - 3 * l;
        int clo = l + 16 * kp, chi = clo + 8;
        ws[4608 + 2 * t2]     = (h16)Wp1[clo * 24 + k];
        ws[4608 + 2 * t2 + 1] = (h16)Wp1[chi * 24 + k];
    }
}

// v7 = R4 (290us best) with the D-phase dot2 GEMM replaced by R5's verified
// MFMA core, minus R5's three overheads: (1) NO staging LDS - A-fragments
// ds_read_b128 directly from the per-group h1 tiles (LDS stays 17.9 KB ->
// same 8 blocks/CU as R4); (2) cfr[5][3] accumulators are pure MFMA C/D
// operands (AGPR candidates) and acc[9][6] is only born at extraction, so
// peak register demand never stacks both; (3) same per-p sync structure as
// R4. 45 MFMA (~225 cyc, MFMA pipe) replace 2592 v_dot2 (~5184 VALU cyc)
// per wave-iteration. Extraction code verbatim from R5 (numerically proven).
__global__ __launch_bounds__(128, 4) void gnn_gat_kernel(
    const float* __restrict__ obs, const float* __restrict__ adj,
    const float* __restrict__ W1,  const float* __restrict__ a1,
    const float* __restrict__ a2,  const float* __restrict__ bp1,
    const float* __restrict__ Wp2, const h16* __restrict__ ws,
    float* __restrict__ out, int B)
{
    __shared__ float sW1[96];
    __shared__ float sC12[6];
    __shared__ unsigned sRb[9];     // per-row 9-bit adjacency masks
    __shared__ __align__(16) float smem[16 * GSCR];

    const int tid = threadIdx.x;
    if (tid < 96) sW1[tid] = W1[tid];
    if (tid < 9) {
        unsigned u = 0;
        for (int j = 0; j < 9; ++j)
            u |= (adj[tid * 9 + j] > 0.f ? 1u : 0u) << j;
        sRb[tid] = u;
    }
    if (tid < 6) {
        int gg = tid >> 1, w = tid & 1;
        float s = 0.f;
        for (int d = 0; d < 32; ++d)
            s += W1[gg * 32 + d] * a1[gg * 64 + w * 32 + d];
        sC12[tid] = s;
    }
    __syncthreads();

    const int wv = tid >> 6, lane = tid & 63;
    const int q = lane >> 3, l8 = lane & 7;
    const int lm = lane & 15, lg = lane >> 4;     // MFMA fragment coords
    float* g  = smem + (wv * 8 + q) * GSCR;
    float* cb = smem + wv * 8 * GSCR;             // C-extract overlay (wave base)
    float4* hUf4 = (float4*)(g + O_U);            // h1 tile rows: 4 float4 each
    float4* h2f4 = (float4*)g;                    // h2 rows: 6 float4 each
    const float4* wsf4 = (const float4*)ws;

    const int slots = gridDim.x * 16;
    for (int b = (blockIdx.x * 2 + wv) * 8 + q; b < B; b += slots) {
        // ---- A: obs into registers (static use only) + LDS copy (runtime use) ----
        float o_r[9];
        #pragma unroll
        for (int j = 0; j < 9; ++j) o_r[j] = obs[(size_t)b * 9 + j];
        g[O_F1 + l8] = obs[(size_t)b * 9 + l8];
        if (l8 == 0) g[O_F1 + 8] = obs[(size_t)b * 9 + 8];
        WAVE_SYNC();

        // ---- B: layer-1 collapsed attention -> s[g][n] in LDS ----
        #pragma unroll
        for (int it = 0; it < 4; ++it) {
            int t = l8 + 8 * it;
            if (t < 27) {
                int gg = (t >= 18) ? 2 : (t >= 9 ? 1 : 0);
                int n = t - 9 * gg;
                float f1 = sC12[2 * gg] * g[O_F1 + n];   // LDS lookups (runtime n, gg)
                float c2 = sC12[2 * gg + 1];
                unsigned rbits = sRb[n];
                float e[9], m = -3.0e38f;
                #pragma unroll
                for (int j = 0; j < 9; ++j) {
                    float x = f1 + c2 * o_r[j];
                    x = x > 0.f ? x : ALPHA * x;
                    x = ((rbits >> j) & 1) ? x : MASKV;
                    e[j] = x; m = fmaxf(m, x);
                }
                float sum = 0.f, sw = 0.f;
                #pragma unroll
                for (int j = 0; j < 9; ++j) {
                    float p = __expf(e[j] - m);
                    sum += p; sw += p * o_r[j];
                }
                g[O_S + t] = sw * fast_rcp(sum);
            }
        }
        WAVE_SYNC();

        // ---- C/D: 3 K-tiles of 32; h1 f16 in per-group LDS, GEMM via MFMA ----
        f32x4 cfr[5][3];
        #pragma unroll
        for (int mt = 0; mt < 5; ++mt)
            #pragma unroll
            for (int nt = 0; nt < 3; ++nt)
                cfr[mt][nt] = (f32x4){0.f, 0.f, 0.f, 0.f};

        for (int p = 0; p < 3; ++p) {
            // C: h1[n][0..31] = elu(s[p][n] * W1[32p..32p+31]) as f16
            #pragma unroll
            for (int it = 0; it < 5; ++it) {
                int t = l8 + 8 * it;
                if (t < 36) {
                    int n = t >> 2, ib = t & 3;
                    int i0 = 32 * p + 8 * ib;
                    float sv = g[O_S + p * 9 + n];
                    float4 wa = *(const float4*)&sW1[i0];
                    float4 wb = *(const float4*)&sW1[i0 + 4];
                    float v0 = sv * wa.x, v1 = sv * wa.y, v2 = sv * wa.z, v3 = sv * wa.w;
                    float v4 = sv * wb.x, v5 = sv * wb.y, v6 = sv * wb.z, v7 = sv * wb.w;
                    v0 = v0 > 0.f ? v0 : __expf(v0) - 1.f;
                    v1 = v1 > 0.f ? v1 : __expf(v1) - 1.f;
                    v2 = v2 > 0.f ? v2 : __expf(v2) - 1.f;
                    v3 = v3 > 0.f ? v3 : __expf(v3) - 1.f;
                    v4 = v4 > 0.f ? v4 : __expf(v4) - 1.f;
                    v5 = v5 > 0.f ? v5 : __expf(v5) - 1.f;
                    v6 = v6 > 0.f ? v6 : __expf(v6) - 1.f;
                    v7 = v7 > 0.f ? v7 : __expf(v7) - 1.f;
                    U4 u;
                    u.h[0] = (v2h){(h16)v0, (h16)v1};
                    u.h[1] = (v2h){(h16)v2, (h16)v3};
                    u.h[2] = (v2h){(h16)v4, (h16)v5};
                    u.h[3] = (v2h){(h16)v6, (h16)v7};
                    hUf4[n * 4 + ib] = u.f;
                }
            }
            WAVE_SYNC();

            // D: A-fragments straight from the 8 per-group h1 tiles.
            // row r = 16mt+lm (clamped to 71; rows 72-79 are never extracted),
            // group q_r = r/9 via magic, node n_r = r%9; k-window = 32p+8lg.
            f16x8 af[5];
            #pragma unroll
            for (int mt = 0; mt < 5; ++mt) {
                int r = 16 * mt + lm;
                if (r > 71) r = 71;
                int qr = (r * 57) >> 9;
                int nr = r - 9 * qr;
                const h16* src = (const h16*)smem
                    + ((wv * 8 + qr) * GSCR + O_U) * 2 + nr * 32 + 8 * lg;
                af[mt] = *(const f16x8*)src;
            }
            #pragma unroll
            for (int nt = 0; nt < 3; ++nt) {
                // B fragment: B[k][c] = ws[c*96 + k], c = 16nt+lm, same k-window
                f16x8 bf = *(const f16x8*)(ws + (16 * nt + lm) * 96 + 32 * p + 8 * lg);
                #pragma unroll
                for (int mt = 0; mt < 5; ++mt)
                    cfr[mt][nt] = __builtin_amdgcn_mfma_f32_16x16x32_f16(
                        af[mt], bf, cfr[mt][nt], 0, 0, 0);
            }
            WAVE_SYNC();   // h1 reads done before next p overwrites
        }

        // ---- C-extract: fragments -> per-group acc[n][k] via LDS overlay ----
        // (verbatim from R5, numerically verified; s/h1 regions are dead here)
        float acc[9][6];
        #pragma unroll
        for (int nt = 0; nt < 3; ++nt) {
            #pragma unroll
            for (int mt = 0; mt < 5; ++mt) {
                int rbase = 16 * mt + 4 * lg;
                #pragma unroll
                for (int r = 0; r < 4; ++r) {
                    int row = rbase + r;
                    if (row < 72) cb[row * CBS + lm] = cfr[mt][nt][r];
                }
            }
            WAVE_SYNC();
            #pragma unroll
            for (int n = 0; n < 9; ++n) {
                int ad = (9 * q + n) * CBS + l8;
                acc[n][2 * nt]     = cb[ad];        // channel l8 + 16nt
                acc[n][2 * nt + 1] = cb[ad + 8];    // channel l8 + 8 + 16nt
            }
            WAVE_SYNC();
        }

        // ---- f1/f2 for layer-2 attention (butterfly over 8 d-lanes) ----
        #pragma unroll
        for (int h = 0; h < 3; ++h) {
            float aa0 = a2[h * 32 + l8];
            float aa1 = a2[h * 32 + 8 + l8];
            float ab0 = a2[h * 32 + 16 + l8];
            float ab1 = a2[h * 32 + 24 + l8];
            #pragma unroll
            for (int n = 0; n < 9; ++n) {
                float v1 = acc[n][2 * h] * aa0 + acc[n][2 * h + 1] * aa1;
                float v2 = acc[n][2 * h] * ab0 + acc[n][2 * h + 1] * ab1;
                v1 += __shfl_xor(v1, 1, 8); v1 += __shfl_xor(v1, 2, 8); v1 += __shfl_xor(v1, 4, 8);
                v2 += __shfl_xor(v2, 1, 8); v2 += __shfl_xor(v2, 2, 8); v2 += __shfl_xor(v2, 4, 8);
                if (((h * 9 + n) & 7) == l8) {
                    g[O_F1 + h * 9 + n]  = v1;
                    g[O_F2 + h * 10 + n] = v2;
                }
            }
        }
        WAVE_SYNC();

        // ---- E1: att rows -> f16 LDS [27][12] ----
        #pragma unroll
        for (int it = 0; it < 4; ++it) {
            int t = l8 + 8 * it;
            if (t < 27) {
                int h = (t >= 18) ? 2 : (t >= 9 ? 1 : 0);
                int i = t - 9 * h;
                float f1i = g[O_F1 + t];
                unsigned rbits = sRb[i];
                float e[9], m = -3.0e38f;
                #pragma unroll
                for (int j = 0; j < 9; ++j) {
                    float x = f1i + g[O_F2 + h * 10 + j];   // direct LDS read
                    x = x > 0.f ? x : ALPHA * x;
                    x = ((rbits >> j) & 1) ? x : MASKV;
                    e[j] = x; m = fmaxf(m, x);
                }
                float p[9], sum = 0.f;
                #pragma unroll
                for (int j = 0; j < 9; ++j) { p[j] = __expf(e[j] - m); sum += p[j]; }
                float r = fast_rcp(sum);
                char* row = (char*)(g + O_U) + t * 24;
                U2 u01, u23; U1 u4;
                u01.h[0] = (v2h){(h16)(p[0] * r), (h16)(p[1] * r)};
                u01.h[1] = (v2h){(h16)(p[2] * r), (h16)(p[3] * r)};
                u23.h[0] = (v2h){(h16)(p[4] * r), (h16)(p[5] * r)};
                u23.h[1] = (v2h){(h16)(p[6] * r), (h16)(p[7] * r)};
                u4.h     = (v2h){(h16)(p[8] * r), (h16)0.f};
                *(float2*)(row)      = u01.f;
                *(float2*)(row + 8)  = u23.f;
                *(float*)(row + 16)  = u4.f;
            }
        }
        WAVE_SYNC();

        // ---- E2: h2 = att @ Wh2, in place into acc ----
        #pragma unroll
        for (int h = 0; h < 3; ++h) {
            float t0[9], t1[9];
            #pragma unroll
            for (int i = 0; i < 9; ++i) {
                const char* row = (const char*)(g + O_U) + (h * 9 + i) * 24;
                U2 a01, a23; U1 a4;
                a01.f = *(const float2*)row;
                a23.f = *(const float2*)(row + 8);
                a4.f  = *(const float*)(row + 16);
                float pj[9];
                pj[0] = (float)a01.h[0].x; pj[1] = (float)a01.h[0].y;
                pj[2] = (float)a01.h[1].x; pj[3] = (float)a01.h[1].y;
                pj[4] = (float)a23.h[0].x; pj[5] = (float)a23.h[0].y;
                pj[6] = (float)a23.h[1].x; pj[7] = (float)a23.h[1].y;
                pj[8] = (float)a4.h.x;
                float s0 = 0.f, s1 = 0.f;
                #pragma unroll
                for (int j = 0; j < 9; ++j) {
                    s0 += pj[j] * acc[j][2 * h];
                    s1 += pj[j] * acc[j][2 * h + 1];
                }
                t0[i] = s0; t1[i] = s1;
            }
            #pragma unroll
            for (int i = 0; i < 9; ++i) { acc[i][2 * h] = t0[i]; acc[i][2 * h + 1] = t1[i]; }
        }

        // ---- F0: pack h2 to f16 pair-slots in LDS (overlay at group base) ----
        #pragma unroll
        for (int n = 0; n < 9; ++n) {
            #pragma unroll
            for (int kp = 0; kp < 3; ++kp) {
                U1 u; u.h = (v2h){(h16)acc[n][2 * kp], (h16)acc[n][2 * kp + 1]};
                ((float*)g)[n * 24 + 3 * l8 + kp] = u.f;
            }
        }
        WAVE_SYNC();

        // ---- F+G: scores via dot2 against pre-packed Wp1; butterfly once per n ----
        float sp[9];
        #pragma unroll
        for (int n = 0; n < 9; ++n) sp[n] = 0.f;
        #pragma unroll
        for (int kk = 0; kk < 3; ++kk) {
            int k = l8 + 8 * kk;
            float wqv = Wp2[k];
            float bqv = bp1[k];
            U4 w0, w1, w2u, w3, w4, w5;
            w0.f = wsf4[576 + k * 6 + 0];
            w1.f = wsf4[576 + k * 6 + 1];
            w2u.f = wsf4[576 + k * 6 + 2];
            w3.f = wsf4[576 + k * 6 + 3];
            w4.f = wsf4[576 + k * 6 + 4];
            w5.f = wsf4[576 + k * 6 + 5];
            #pragma unroll
            for (int n = 0; n < 9; ++n) {
                float a = 0.f;
                U4 x;
                x.f = h2f4[n * 6 + 0];
                a = FDOT2(x.h[0], w0.h[0], a); a = FDOT2(x.h[1], w0.h[1], a);
                a = FDOT2(x.h[2], w0.h[2], a); a = FDOT2(x.h[3], w0.h[3], a);
                x.f = h2f4[n * 6 + 1];
                a = FDOT2(x.h[0], w1.h[0], a); a = FDOT2(x.h[1], w1.h[1], a);
                a = FDOT2(x.h[2], w1.h[2], a); a = FDOT2(x.h[3], w1.h[3], a);
                x.f = h2f4[n * 6 + 2];
                a = FDOT2(x.h[0], w2u.h[0], a); a = FDOT2(x.h[1], w2u.h[1], a);
                a = FDOT2(x.h[2], w2u.h[2], a); a = FDOT2(x.h[3], w2u.h[3], a);
                x.f = h2f4[n * 6 + 3];
                a = FDOT2(x.h[0], w3.h[0], a); a = FDOT2(x.h[1], w3.h[1], a);
                a = FDOT2(x.h[2], w3.h[2], a); a = FDOT2(x.h[3], w3.h[3], a);
                x.f = h2f4[n * 6 + 4];
                a = FDOT2(x.h[0], w4.h[0], a); a = FDOT2(x.h[1], w4.h[1], a);
                a = FDOT2(x.h[2], w4.h[2], a); a = FDOT2(x.h[3], w4.h[3], a);
                x.f = h2f4[n * 6 + 5];
                a = FDOT2(x.h[0], w5.h[0], a); a = FDOT2(x.h[1], w5.h[1], a);
                a = FDOT2(x.h[2], w5.h[2], a); a = FDOT2(x.h[3], w5.h[3], a);
                float tv = tanh_fast(a + bqv);
                sp[n] += tv * wqv;
            }
        }
        #pragma unroll
        for (int n = 0; n < 9; ++n) {
            sp[n] += __shfl_xor(sp[n], 1, 8);
            sp[n] += __shfl_xor(sp[n], 2, 8);
            sp[n] += __shfl_xor(sp[n], 4, 8);
        }

        // ---- H: node softmax (bp2 cancels) + weighted sum -> out ----
        float mx = sp[0];
        #pragma unroll
        for (int n = 1; n < 9; ++n) mx = fmaxf(mx, sp[n]);
        float wn9[9], sum = 0.f;
        #pragma unroll
        for (int n = 0; n < 9; ++n) { wn9[n] = __expf(sp[n] - mx); sum += wn9[n]; }
        float r = fast_rcp(sum);
        #pragma unroll
        for (int k = 0; k < 6; ++k) {
            float ov = 0.f;
            #pragma unroll
            for (int n = 0; n < 9; ++n) ov += wn9[n] * acc[n][k];
            out[(size_t)b * 48 + l8 + 8 * k] = ov * r;
        }
        WAVE_SYNC();
    }
}

extern "C" void kernel_launch(void* const* d_in, const int* in_sizes, int n_in,
                              void* d_out, int out_size, void* d_ws, size_t ws_size,
                              hipStream_t stream) {
    const float* obs = (const float*)d_in[0];
    const float* adj = (const float*)d_in[1];
    const float* W1  = (const float*)d_in[2];
    const float* a1  = (const float*)d_in[3];
    const float* W2  = (const float*)d_in[4];
    const float* a2  = (const float*)d_in[5];
    const float* Wp1 = (const float*)d_in[6];
    const float* bp1 = (const float*)d_in[7];
    const float* Wp2 = (const float*)d_in[8];
    float* out = (float*)d_out;
    h16* ws = (h16*)d_ws;

    const int B = in_sizes[0] / 9;

    prep_kernel<<<(48 * 96 + 576 + 255) / 256, 256, 0, stream>>>(W2, Wp1, ws);

    gnn_gat_kernel<<<4096, 128, 0, stream>>>(
        obs, adj, W1, a1, a2, bp1, Wp2, ws, out, B);
}